// Round 7
// baseline (324.932 us; speedup 1.0000x reference)
//
#include <hip/hip_runtime.h>

#define DEV __device__ __forceinline__

typedef __attribute__((ext_vector_type(8))) short short8;
typedef __attribute__((ext_vector_type(4))) float floatx4;
typedef __attribute__((ext_vector_type(4))) int i32x4;
typedef __attribute__((ext_vector_type(2))) long longx2;

DEV unsigned short f2bs(float x) {
    unsigned u = __float_as_uint(x);
    unsigned r = (u + 0x7fffu + ((u >> 16) & 1u)) >> 16;
    return (unsigned short)r;
}

// f32 -> OCP e4m3fn. Caller must pre-clamp to [-448, 448].
DEV unsigned char f2fp8(float x) {
#if __has_builtin(__builtin_amdgcn_cvt_pk_fp8_f32)
    int pk = __builtin_amdgcn_cvt_pk_fp8_f32(x, 0.f, 0, false);
    return (unsigned char)(pk & 0xff);
#else
    unsigned u = __float_as_uint(x);
    unsigned s = (u >> 24) & 0x80;
    u &= 0x7fffffff;
    unsigned um = u + 0x7ffff + ((u >> 20) & 1);
    int e = (int)(um >> 23) - 120;
    unsigned char r;
    if (e <= 0) {
        float ax = __uint_as_float(u);
        int q = (int)rintf(ax * 512.f);
        r = (unsigned char)((q > 7) ? 8 : q);
    } else {
        r = (unsigned char)((e << 3) | ((um >> 20) & 7));
    }
    return r | s;
#endif
}

DEV unsigned pack_fp8x4(float v0, float v1, float v2, float v3) {
#if __has_builtin(__builtin_amdgcn_cvt_pk_fp8_f32)
    unsigned pk = (unsigned)__builtin_amdgcn_cvt_pk_fp8_f32(v0, v1, 0, false);
    pk = (unsigned)__builtin_amdgcn_cvt_pk_fp8_f32(v2, v3, (int)pk, true);
    return pk;
#else
    return (unsigned)f2fp8(v0) | ((unsigned)f2fp8(v1) << 8) |
           ((unsigned)f2fp8(v2) << 16) | ((unsigned)f2fp8(v3) << 24);
#endif
}

DEV unsigned pack_i8x4(float v0, float v1, float v2, float v3) {
    unsigned b0 = (unsigned)((int)rintf(v0)) & 255u;
    unsigned b1 = (unsigned)((int)rintf(v1)) & 255u;
    unsigned b2 = (unsigned)((int)rintf(v2)) & 255u;
    unsigned b3 = (unsigned)((int)rintf(v3)) & 255u;
    return b0 | (b1 << 8) | (b2 << 16) | (b3 << 24);
}

// ---------------- GroupNorm stats: one block per (b,g); also zeroes rowsum ----------------
__global__ void gn_stats_kernel(const float* __restrict__ x, float* __restrict__ stats,
                                float* __restrict__ rowsum) {
    int bg = blockIdx.x;  // 0..127
    int tid = threadIdx.x;
    if (tid < 128) rowsum[bg * 128 + tid] = 0.f;
    const float4* p = (const float4*)(x + (size_t)bg * 65536);
    float s = 0.f, ss = 0.f;
    for (int i = tid; i < 16384; i += 256) {
        float4 v = p[i];
        s += v.x + v.y + v.z + v.w;
        ss += v.x * v.x + v.y * v.y + v.z * v.z + v.w * v.w;
    }
    for (int off = 32; off; off >>= 1) { s += __shfl_down(s, off); ss += __shfl_down(ss, off); }
    __shared__ float rs[4], rss[4];
    int wave = tid >> 6, lane = tid & 63;
    if (lane == 0) { rs[wave] = s; rss[wave] = ss; }
    __syncthreads();
    if (tid == 0) {
        float S = rs[0] + rs[1] + rs[2] + rs[3];
        float SS = rss[0] + rss[1] + rss[2] + rss[3];
        float mean = S * (1.f / 65536.f);
        float var = SS * (1.f / 65536.f) - mean * mean;
        stats[bg * 2] = mean;
        stats[bg * 2 + 1] = rsqrtf(var + 1e-5f);
    }
}

// ------------- GN apply + transpose: x[b][c][p] fp32 -> h_t[b][p][c] bf16 -------------
__global__ void gn_apply_kernel(const float* __restrict__ x, const float* __restrict__ stats,
                                const float* __restrict__ gw, const float* __restrict__ gb,
                                unsigned short* __restrict__ ht) {
    __shared__ __align__(16) unsigned short t[64][72];
    int b = blockIdx.z, c0 = blockIdx.y * 64, p0 = blockIdx.x * 64;
    int tid = threadIdx.x;
    const float* xb = x + ((size_t)b * 512 + c0) * 4096 + p0;
#pragma unroll
    for (int pass = 0; pass < 4; ++pass) {
        int cl = pass * 16 + (tid >> 4);
        int pq = (tid & 15) * 4;
        float4 v = *(const float4*)(xb + (size_t)cl * 4096 + pq);
        int c = c0 + cl, g = c >> 4;
        float mean = stats[(b * 32 + g) * 2], rstd = stats[(b * 32 + g) * 2 + 1];
        float sw = gw[c] * rstd;
        float sb = gb[c] - mean * sw;
        t[pq + 0][cl] = f2bs(v.x * sw + sb);
        t[pq + 1][cl] = f2bs(v.y * sw + sb);
        t[pq + 2][cl] = f2bs(v.z * sw + sb);
        t[pq + 3][cl] = f2bs(v.w * sw + sb);
    }
    __syncthreads();
    unsigned short* hb = ht + ((size_t)b * 4096 + p0) * 512 + c0;
#pragma unroll
    for (int pass = 0; pass < 2; ++pass) {
        int pl = pass * 32 + (tid >> 3);
        int c8 = (tid & 7) * 8;
        *(uint4*)(hb + (size_t)pl * 512 + c8) = *(const uint4*)&t[pl][c8];
    }
}

// ---------------- fp32 -> bf16 weight convert ----------------
__global__ void cvt_bf16_kernel(const float* __restrict__ s, unsigned short* __restrict__ d, int n4) {
    int i = blockIdx.x * 256 + threadIdx.x;
    if (i >= n4) return;
    float4 v = ((const float4*)s)[i];
    ushort4 o;
    o.x = f2bs(v.x); o.y = f2bs(v.y); o.z = f2bs(v.z); o.w = f2bs(v.w);
    ((ushort4*)d)[i] = o;
}

// ---------------- NT GEMM: C[m][n] = sum_k A[m][k]*B[n][k], bf16 in, fp32 acc ----------------
// LDS XOR-swizzled: LDS[row][chunk j] = global[row][j ^ (row&7)] (chunk = 16B).
// Byte outputs (EPI 0/5) use the pack4 permuted layout: within each 64-col
// block, logical col j*16+lc is stored at lc*4+j. Consumers (i8/fp8 GEMMs)
// see both their operands permuted identically, so dot products are unchanged.
// EPI: 0 = i8 out = clamp(round((v+bias[n])*scale)), split Cv/Cv2 at NS, pack4
//      4 = f32 out + bias[m] + residual
//      5 = fp8 e4m3 out = v + bias[m], pack4
template <int EPI>
__global__ void gemm_nt(const unsigned short* __restrict__ A, long long sAb,
                        const unsigned short* __restrict__ B, long long sBb,
                        void* __restrict__ Cv, void* __restrict__ Cv2, long long sCb,
                        const float* __restrict__ bias,
                        const float* __restrict__ resid, long long sRb,
                        int M, int N, int K, int Nst, int NS, float scale) {
    __shared__ __align__(16) unsigned short lA[128 * 64];
    __shared__ __align__(16) unsigned short lB[128 * 64];
    const int tid = threadIdx.x;
    const int wave = tid >> 6, lane = tid & 63;
    const int m0 = blockIdx.y * 128, n0 = blockIdx.x * 128, bz = blockIdx.z;
    const unsigned short* Ab = A + (size_t)bz * sAb;
    const unsigned short* Bb = B + (size_t)bz * sBb;

    floatx4 acc[4][4];
#pragma unroll
    for (int i = 0; i < 4; i++)
#pragma unroll
        for (int j = 0; j < 4; j++) acc[i][j] = (floatx4){0.f, 0.f, 0.f, 0.f};

    const int wm = (wave >> 1) * 64, wn = (wave & 1) * 64;
    const int quad = lane >> 4;   // 0..3
    const int lc = lane & 15;     // 0..15
    const int lc7 = lc & 7;

    const int nk = K >> 6;
    for (int kt = 0; kt < nk; ++kt) {
        const int kbase = kt * 64;
#pragma unroll
        for (int c = 0; c < 4; ++c) {
            int d = c * 256 + tid;            // 16B-chunk index within tile
            int r = d >> 3;                   // row 0..127
            int kc = (d & 7) ^ (r & 7);       // swizzled source k-chunk
            const unsigned short* ga = Ab + (size_t)(m0 + r) * K + kbase + kc * 8;
            const unsigned short* gb = Bb + (size_t)(n0 + r) * K + kbase + kc * 8;
            __builtin_amdgcn_global_load_lds(
                (const __attribute__((address_space(1))) void*)ga,
                (__attribute__((address_space(3))) void*)&lA[(size_t)(c * 256 + wave * 64) * 8], 16, 0, 0);
            __builtin_amdgcn_global_load_lds(
                (const __attribute__((address_space(1))) void*)gb,
                (__attribute__((address_space(3))) void*)&lB[(size_t)(c * 256 + wave * 64) * 8], 16, 0, 0);
        }
        __syncthreads();
#pragma unroll
        for (int kk = 0; kk < 2; ++kk) {
            const int swz = ((kk * 4 + quad) ^ lc7) * 8;
            short8 af[4], bf[4];
#pragma unroll
            for (int i = 0; i < 4; i++)
                af[i] = *(const short8*)&lA[(size_t)(wm + i * 16 + lc) * 64 + swz];
#pragma unroll
            for (int j = 0; j < 4; j++)
                bf[j] = *(const short8*)&lB[(size_t)(wn + j * 16 + lc) * 64 + swz];
#pragma unroll
            for (int i = 0; i < 4; i++)
#pragma unroll
                for (int j = 0; j < 4; j++)
                    acc[i][j] = __builtin_amdgcn_mfma_f32_16x16x32_bf16(af[i], bf[j], acc[i][j], 0, 0, 0);
        }
        __syncthreads();
    }

    // epilogue: D row = quad*4 + reg, col = lane&15
    const int rowb = quad * 4;
#pragma unroll
    for (int i = 0; i < 4; i++) {
#pragma unroll
        for (int r = 0; r < 4; r++) {
            const int m = m0 + wm + i * 16 + rowb + r;
            if constexpr (EPI == 0) {
                float q[4];
#pragma unroll
                for (int j = 0; j < 4; j++) {
                    const int n = n0 + wn + j * 16 + lc;
                    q[j] = fminf(fmaxf((acc[i][j][r] + bias[n]) * scale, -127.f), 127.f);
                }
                const int col64 = n0 + wn;
                char* outp = (char*)((col64 < NS) ? Cv : Cv2);
                size_t idx = (size_t)bz * sCb + (size_t)m * Nst +
                             (col64 - ((col64 < NS) ? 0 : NS)) + lc * 4;
                *(unsigned*)(outp + idx) = pack_i8x4(q[0], q[1], q[2], q[3]);
            } else if constexpr (EPI == 5) {
                const float bm = bias[m];
                float q[4];
#pragma unroll
                for (int j = 0; j < 4; j++)
                    q[j] = fminf(fmaxf(acc[i][j][r] + bm, -448.f), 448.f);
                size_t idx = (size_t)bz * sCb + (size_t)m * Nst + n0 + wn + lc * 4;
                *(unsigned*)((char*)Cv + idx) = pack_fp8x4(q[0], q[1], q[2], q[3]);
            } else {
#pragma unroll
                for (int j = 0; j < 4; j++) {
                    const int n = n0 + wn + j * 16 + lc;
                    size_t idx = (size_t)bz * sCb + (size_t)m * Nst + n;
                    ((float*)Cv)[idx] = acc[i][j][r] + bias[m] +
                                        resid[(size_t)bz * sRb + (size_t)m * Nst + n];
                }
            }
        }
    }
}

// ---------------- i8 NT GEMM: P = e4m3(0.25*exp(qk*scale)), pack4 layout, rowsum atomics ----------------
// scale2 = scale*log2(e); e = 2^(acc*scale2 - 2) == 0.25*exp(acc*scale).
__global__ void gemm_i8_exp(const char* __restrict__ A, long long sAb,
                            const char* __restrict__ B, long long sBb,
                            char* __restrict__ Cv, long long sCb,
                            float* __restrict__ rowsum,
                            int M, int N, int K, float scale2) {
    __shared__ __align__(16) char lA[128 * 128];
    __shared__ __align__(16) char lB[128 * 128];
    const int tid = threadIdx.x;
    const int wave = tid >> 6, lane = tid & 63;
    const int m0 = blockIdx.y * 128, n0 = blockIdx.x * 128, bz = blockIdx.z;
    const char* Ab = A + (size_t)bz * sAb;
    const char* Bb = B + (size_t)bz * sBb;

    i32x4 acc[4][4];
#pragma unroll
    for (int i = 0; i < 4; i++)
#pragma unroll
        for (int j = 0; j < 4; j++) acc[i][j] = (i32x4){0, 0, 0, 0};

    const int wm = (wave >> 1) * 64, wn = (wave & 1) * 64;
    const int quad = lane >> 4;
    const int lc = lane & 15;
    const int lc7 = lc & 7;

    const int nk = K >> 7;
    for (int kt = 0; kt < nk; ++kt) {
        const int kbase = kt * 128;
#pragma unroll
        for (int c = 0; c < 4; ++c) {
            int d = c * 256 + tid;
            int r = d >> 3;
            int kc = (d & 7) ^ (r & 7);
            const char* ga = Ab + (size_t)(m0 + r) * K + kbase + kc * 16;
            const char* gb = Bb + (size_t)(n0 + r) * K + kbase + kc * 16;
            __builtin_amdgcn_global_load_lds(
                (const __attribute__((address_space(1))) void*)ga,
                (__attribute__((address_space(3))) void*)&lA[(size_t)(c * 256 + wave * 64) * 16], 16, 0, 0);
            __builtin_amdgcn_global_load_lds(
                (const __attribute__((address_space(1))) void*)gb,
                (__attribute__((address_space(3))) void*)&lB[(size_t)(c * 256 + wave * 64) * 16], 16, 0, 0);
        }
        __syncthreads();
#pragma unroll
        for (int kk = 0; kk < 2; ++kk) {
            const int swz = ((kk * 4 + quad) ^ lc7) * 16;
            i32x4 af[4], bf[4];
#pragma unroll
            for (int i = 0; i < 4; i++)
                af[i] = *(const i32x4*)&lA[(size_t)(wm + i * 16 + lc) * 128 + swz];
#pragma unroll
            for (int j = 0; j < 4; j++)
                bf[j] = *(const i32x4*)&lB[(size_t)(wn + j * 16 + lc) * 128 + swz];
#pragma unroll
            for (int i = 0; i < 4; i++)
#pragma unroll
                for (int j = 0; j < 4; j++)
                    acc[i][j] = __builtin_amdgcn_mfma_i32_16x16x64_i8(af[i], bf[j], acc[i][j], 0, 0, 0);
        }
        __syncthreads();
    }

    const int rowb = quad * 4;
#pragma unroll
    for (int i = 0; i < 4; i++) {
#pragma unroll
        for (int r = 0; r < 4; r++) {
            const int m = m0 + wm + i * 16 + rowb + r;
            float e[4];
            float rsacc = 0.f;
#pragma unroll
            for (int j = 0; j < 4; j++) {
                e[j] = fminf(exp2f(fmaf((float)acc[i][j][r], scale2, -2.0f)), 448.f);
                rsacc += e[j];
            }
            size_t idx = (size_t)bz * sCb + (size_t)m * N + n0 + wn + lc * 4;
            *(unsigned*)(Cv + idx) = pack_fp8x4(e[0], e[1], e[2], e[3]);
            rsacc += __shfl_xor(rsacc, 1);
            rsacc += __shfl_xor(rsacc, 2);
            rsacc += __shfl_xor(rsacc, 4);
            rsacc += __shfl_xor(rsacc, 8);
            if (lc == 0) atomicAdd(&rowsum[(size_t)bz * M + m], rsacc);
        }
    }
}

// ---------------- fp8 NT GEMM: O_t[q][d] = (sum_k P[q][k]*V[d][k]) / rowsum[q], bf16 out ----------------
// K-tile = 128 fp8 (128B/row). XCD-swizzled flat grid (512 blocks), M=4096, N=512, K=4096.
// P and V share the pack4 column permutation, which cancels in the dot product.
__global__ void gemm_fp8_o(const char* __restrict__ A, long long sAb,
                           const char* __restrict__ B, long long sBb,
                           unsigned short* __restrict__ Cv, long long sCb,
                           const float* __restrict__ rowsum,
                           int M, int N, int K) {
    __shared__ __align__(16) char lA[128 * 128];
    __shared__ __align__(16) char lB[128 * 128];
    const int tid = threadIdx.x;
    const int wave = tid >> 6, lane = tid & 63;
    int flat = blockIdx.x;
    int xcd = flat & 7, idx = flat >> 3;
    int nt = idx & 3, si = idx >> 2;
    int stripe = xcd * 16 + si;
    const int m0 = (stripe & 31) * 128;
    const int n0 = nt * 128;
    const int bz = stripe >> 5;
    const char* Ab = A + (size_t)bz * sAb;
    const char* Bb = B + (size_t)bz * sBb;

    floatx4 acc[4][4];
#pragma unroll
    for (int i = 0; i < 4; i++)
#pragma unroll
        for (int j = 0; j < 4; j++) acc[i][j] = (floatx4){0.f, 0.f, 0.f, 0.f};

    const int wm = (wave >> 1) * 64, wn = (wave & 1) * 64;
    const int quad = lane >> 4;
    const int lc = lane & 15;
    const int lc7 = lc & 7;
    const int half = quad & 1;

    const int nk = K >> 7;
    for (int kt = 0; kt < nk; ++kt) {
        const int kbase = kt * 128;
#pragma unroll
        for (int c = 0; c < 4; ++c) {
            int d = c * 256 + tid;
            int r = d >> 3;
            int kc = (d & 7) ^ (r & 7);
            const char* ga = Ab + (size_t)(m0 + r) * K + kbase + kc * 16;
            const char* gb = Bb + (size_t)(n0 + r) * K + kbase + kc * 16;
            __builtin_amdgcn_global_load_lds(
                (const __attribute__((address_space(1))) void*)ga,
                (__attribute__((address_space(3))) void*)&lA[(size_t)(c * 256 + wave * 64) * 16], 16, 0, 0);
            __builtin_amdgcn_global_load_lds(
                (const __attribute__((address_space(1))) void*)gb,
                (__attribute__((address_space(3))) void*)&lB[(size_t)(c * 256 + wave * 64) * 16], 16, 0, 0);
        }
        __syncthreads();
#pragma unroll
        for (int t = 0; t < 4; ++t) {
            const int swz = ((2 * t + (quad >> 1)) ^ lc7) * 16;
            long a8[4], b8[4];
#pragma unroll
            for (int i = 0; i < 4; i++) {
                longx2 v = *(const longx2*)&lA[(size_t)(wm + i * 16 + lc) * 128 + swz];
                a8[i] = v[half];
            }
#pragma unroll
            for (int j = 0; j < 4; j++) {
                longx2 v = *(const longx2*)&lB[(size_t)(wn + j * 16 + lc) * 128 + swz];
                b8[j] = v[half];
            }
#pragma unroll
            for (int i = 0; i < 4; i++)
#pragma unroll
                for (int j = 0; j < 4; j++)
                    acc[i][j] = __builtin_amdgcn_mfma_f32_16x16x32_fp8_fp8(a8[i], b8[j], acc[i][j], 0, 0, 0);
        }
        __syncthreads();
    }

    const int rowb = quad * 4;
#pragma unroll
    for (int i = 0; i < 4; i++) {
#pragma unroll
        for (int r = 0; r < 4; r++) {
            const int m = m0 + wm + i * 16 + rowb + r;
            const float pscale = 1.f / rowsum[(size_t)bz * M + m];
#pragma unroll
            for (int j = 0; j < 4; j++) {
                const int n = n0 + wn + j * 16 + lc;
                Cv[(size_t)bz * sCb + (size_t)m * N + n] = f2bs(acc[i][j][r] * pscale);
            }
        }
    }
}

extern "C" void kernel_launch(void* const* d_in, const int* in_sizes, int n_in,
                              void* d_out, int out_size, void* d_ws, size_t ws_size,
                              hipStream_t stream) {
    (void)in_sizes; (void)n_in; (void)out_size; (void)ws_size;
    const float* x   = (const float*)d_in[0];
    const float* gnw = (const float*)d_in[1];
    const float* gnb = (const float*)d_in[2];
    const float* qw  = (const float*)d_in[3];
    const float* qb  = (const float*)d_in[4];
    const float* kw  = (const float*)d_in[5];
    const float* kb  = (const float*)d_in[6];
    const float* vw  = (const float*)d_in[7];
    const float* vb  = (const float*)d_in[8];
    const float* pw  = (const float*)d_in[9];
    const float* pb  = (const float*)d_in[10];
    float* out = (float*)d_out;

    char* ws = (char*)d_ws;
    unsigned short* h_t = (unsigned short*)(ws);
    unsigned short* o_t = h_t;  // alias: h_t dead after v GEMM
    char* q_i8 = (char*)(ws + (16ull << 20));
    char* k_i8 = (char*)(ws + (32ull << 20));
    char* v_f8 = (char*)(ws + (48ull << 20));
    unsigned short* wqkb = (unsigned short*)(ws + (64ull << 20));  // [qw;kw] 1024x512
    unsigned short* wvb = (unsigned short*)(ws + (65ull << 20));
    unsigned short* wpb = wvb + 262144;
    float* stats  = (float*)(ws + (66ull << 20));
    float* rowsum = (float*)(ws + (66ull << 20) + 65536);
    float* biasqk = (float*)(ws + (66ull << 20) + 131072);
    char* p_f8 = (char*)(ws + (67ull << 20));

    const long long sP  = 2097152;   // 4096*512 elements per batch
    const long long sS  = 16777216;  // 4096*4096 bytes per batch (fp8 P)
    const int BIG = 1 << 30;
    const float QS = 16.f;
    const float SC = 0.044194173824159216f / (QS * QS);
    const float LOG2E = 1.4426950408889634f;

    cvt_bf16_kernel<<<256, 256, 0, stream>>>(qw, wqkb, 65536);
    cvt_bf16_kernel<<<256, 256, 0, stream>>>(kw, wqkb + 262144, 65536);
    cvt_bf16_kernel<<<256, 256, 0, stream>>>(vw, wvb, 65536);
    cvt_bf16_kernel<<<256, 256, 0, stream>>>(pw, wpb, 65536);
    hipMemcpyAsync(biasqk, qb, 512 * sizeof(float), hipMemcpyDeviceToDevice, stream);
    hipMemcpyAsync(biasqk + 512, kb, 512 * sizeof(float), hipMemcpyDeviceToDevice, stream);
    gn_stats_kernel<<<128, 256, 0, stream>>>(x, stats, rowsum);
    gn_apply_kernel<<<dim3(64, 8, 4), 256, 0, stream>>>(x, stats, gnw, gnb, h_t);
    // merged q|k: M=4096(p), N=1024(o), K=512(c); i8 pack4 outputs split at NS=512
    gemm_nt<0><<<dim3(8, 32, 4), 256, 0, stream>>>(h_t, sP, wqkb, 0, q_i8, k_i8, sP, biasqk,
                                                   nullptr, 0, 4096, 1024, 512, 512, 512, QS);
    // v[d][p] -> e4m3 pack4: M=512(d), N=4096(p), K=512(c)
    gemm_nt<5><<<dim3(32, 4, 4), 256, 0, stream>>>(wvb, 0, h_t, sP, v_f8, v_f8, sP, vb,
                                                   nullptr, 0, 512, 4096, 512, 4096, BIG, 1.f);
    // P[q][k] = e4m3(0.25*exp(qk*SC)) pack4, rowsums of scaled values
    gemm_i8_exp<<<dim3(32, 32, 4), 256, 0, stream>>>(q_i8, sP, k_i8, sP, p_f8, sS, rowsum,
                                                     4096, 4096, 512, SC * LOG2E);
    // O_t[q][d] = (P . v^T)/rowsum: fp8 MFMA, M=4096, N=512, K=4096, XCD-swizzled
    gemm_fp8_o<<<dim3(512, 1, 1), 256, 0, stream>>>(p_f8, sS, v_f8, sP, o_t, sP, rowsum,
                                                    4096, 512, 4096);
    // y = x + pw . O_t^T + pb: M=512(o), N=4096(p), K=512(d)
    gemm_nt<4><<<dim3(32, 4, 4), 256, 0, stream>>>(wpb, 0, o_t, sP, (void*)out, nullptr, sP, pb,
                                                   x, sP, 512, 4096, 512, 4096, BIG, 1.f);
}

// Round 9
// 314.222 us; speedup vs baseline: 1.0341x; 1.0341x over previous
//
#include <hip/hip_runtime.h>

#define DEV __device__ __forceinline__

typedef __attribute__((ext_vector_type(8))) short short8;
typedef __attribute__((ext_vector_type(4))) float floatx4;
typedef __attribute__((ext_vector_type(4))) int i32x4;
typedef __attribute__((ext_vector_type(2))) long longx2;

DEV unsigned short f2bs(float x) {
    unsigned u = __float_as_uint(x);
    unsigned r = (u + 0x7fffu + ((u >> 16) & 1u)) >> 16;
    return (unsigned short)r;
}

// f32 -> OCP e4m3fn. Caller pre-clamps to [-448, 448]. Fallback: branchless, FTZ below 2^-6.
DEV unsigned char f2fp8(float x) {
#if __has_builtin(__builtin_amdgcn_cvt_pk_fp8_f32)
    int pk = __builtin_amdgcn_cvt_pk_fp8_f32(x, 0.f, 0, false);
    return (unsigned char)(pk & 0xff);
#else
    unsigned u = __float_as_uint(x);
    unsigned s = (u >> 24) & 0x80;
    unsigned a = u & 0x7fffffff;
    unsigned um = a + 0x7ffffu + ((a >> 20) & 1u);
    unsigned r = (a >= 0x3c800000u) ? ((um >> 20) - 0x3C0u) : 0u;
    return (unsigned char)(r | s);
#endif
}

DEV unsigned pack_fp8x4(float v0, float v1, float v2, float v3) {
#if __has_builtin(__builtin_amdgcn_cvt_pk_fp8_f32)
    unsigned pk = (unsigned)__builtin_amdgcn_cvt_pk_fp8_f32(v0, v1, 0, false);
    pk = (unsigned)__builtin_amdgcn_cvt_pk_fp8_f32(v2, v3, (int)pk, true);
    return pk;
#else
    return (unsigned)f2fp8(v0) | ((unsigned)f2fp8(v1) << 8) |
           ((unsigned)f2fp8(v2) << 16) | ((unsigned)f2fp8(v3) << 24);
#endif
}

DEV unsigned pack_i8x4(float v0, float v1, float v2, float v3) {
    unsigned b0 = (unsigned)((int)rintf(v0)) & 255u;
    unsigned b1 = (unsigned)((int)rintf(v1)) & 255u;
    unsigned b2 = (unsigned)((int)rintf(v2)) & 255u;
    unsigned b3 = (unsigned)((int)rintf(v3)) & 255u;
    return b0 | (b1 << 8) | (b2 << 16) | (b3 << 24);
}

// ---------------- setup: weight converts (+wp k-permutation), biasqk, rowsum zero ----------------
// grid 1025 x 256. wp's k-columns get the pack4 permutation (within each 64-block,
// col 16j+lc -> 4lc+j) to match o_t's permuted store layout in gemm_fp8_o.
__global__ void setup_kernel(const float* __restrict__ qw, const float* __restrict__ kw,
                             const float* __restrict__ vw, const float* __restrict__ pw,
                             const float* __restrict__ qb, const float* __restrict__ kb,
                             unsigned short* __restrict__ wqkb, unsigned short* __restrict__ wvb,
                             unsigned short* __restrict__ wpb,
                             float* __restrict__ biasqk, float* __restrict__ rowsum) {
    int b = blockIdx.x, tid = threadIdx.x;
    if (b < 768) {
        const float* src = (b < 256) ? qw : (b < 512) ? kw : vw;
        unsigned short* dst = (b < 256) ? wqkb : (b < 512) ? (wqkb + 262144) : wvb;
        int off = (b & 255) * 256 + tid;  // float4 index, 0..65535
        float4 v = ((const float4*)src)[off];
        ushort4 o;
        o.x = f2bs(v.x); o.y = f2bs(v.y); o.z = f2bs(v.z); o.w = f2bs(v.w);
        ((ushort4*)dst)[off] = o;
    } else if (b < 1024) {
        int off = (b - 768) * 256 + tid;  // float4 index into pw
        int row = off >> 7, c4 = (off & 127) * 4;
        float4 v = ((const float4*)pw)[off];
        float vv[4] = {v.x, v.y, v.z, v.w};
#pragma unroll
        for (int e = 0; e < 4; ++e) {
            int c = c4 + e;
            int j = (c >> 4) & 3, lc = c & 15;
            int cp = (c & ~63) | (lc * 4 + j);
            wpb[row * 512 + cp] = f2bs(vv[e]);
        }
    } else {
        biasqk[tid]       = qb[tid];
        biasqk[256 + tid] = qb[256 + tid];
        biasqk[512 + tid] = kb[tid];
        biasqk[768 + tid] = kb[256 + tid];
        float4 z = {0.f, 0.f, 0.f, 0.f};
#pragma unroll
        for (int k = 0; k < 16; ++k) ((float4*)rowsum)[k * 256 + tid] = z;
    }
}

// ---------------- GroupNorm stats: one block per (b,g) ----------------
__global__ void gn_stats_kernel(const float* __restrict__ x, float* __restrict__ stats) {
    int bg = blockIdx.x;  // 0..127
    int tid = threadIdx.x;
    const float4* p = (const float4*)(x + (size_t)bg * 65536);
    float s = 0.f, ss = 0.f;
    for (int i = tid; i < 16384; i += 256) {
        float4 v = p[i];
        s += v.x + v.y + v.z + v.w;
        ss += v.x * v.x + v.y * v.y + v.z * v.z + v.w * v.w;
    }
    for (int off = 32; off; off >>= 1) { s += __shfl_down(s, off); ss += __shfl_down(ss, off); }
    __shared__ float rs[4], rss[4];
    int wave = tid >> 6, lane = tid & 63;
    if (lane == 0) { rs[wave] = s; rss[wave] = ss; }
    __syncthreads();
    if (tid == 0) {
        float S = rs[0] + rs[1] + rs[2] + rs[3];
        float SS = rss[0] + rss[1] + rss[2] + rss[3];
        float mean = S * (1.f / 65536.f);
        float var = SS * (1.f / 65536.f) - mean * mean;
        stats[bg * 2] = mean;
        stats[bg * 2 + 1] = rsqrtf(var + 1e-5f);
    }
}

// ------------- GN apply + transpose: x[b][c][p] fp32 -> h_t[b][p][c] bf16 -------------
__global__ void gn_apply_kernel(const float* __restrict__ x, const float* __restrict__ stats,
                                const float* __restrict__ gw, const float* __restrict__ gb,
                                unsigned short* __restrict__ ht) {
    __shared__ __align__(16) unsigned short t[64][72];
    int b = blockIdx.z, c0 = blockIdx.y * 64, p0 = blockIdx.x * 64;
    int tid = threadIdx.x;
    const float* xb = x + ((size_t)b * 512 + c0) * 4096 + p0;
#pragma unroll
    for (int pass = 0; pass < 4; ++pass) {
        int cl = pass * 16 + (tid >> 4);
        int pq = (tid & 15) * 4;
        float4 v = *(const float4*)(xb + (size_t)cl * 4096 + pq);
        int c = c0 + cl, g = c >> 4;
        float mean = stats[(b * 32 + g) * 2], rstd = stats[(b * 32 + g) * 2 + 1];
        float sw = gw[c] * rstd;
        float sb = gb[c] - mean * sw;
        t[pq + 0][cl] = f2bs(v.x * sw + sb);
        t[pq + 1][cl] = f2bs(v.y * sw + sb);
        t[pq + 2][cl] = f2bs(v.z * sw + sb);
        t[pq + 3][cl] = f2bs(v.w * sw + sb);
    }
    __syncthreads();
    unsigned short* hb = ht + ((size_t)b * 4096 + p0) * 512 + c0;
#pragma unroll
    for (int pass = 0; pass < 2; ++pass) {
        int pl = pass * 32 + (tid >> 3);
        int c8 = (tid & 7) * 8;
        *(uint4*)(hb + (size_t)pl * 512 + c8) = *(const uint4*)&t[pl][c8];
    }
}

// ---------------- NT GEMM: C[m][n] = sum_k A[m][k]*B[n][k], bf16 in, fp32 acc ----------------
// LDS XOR-swizzled: LDS[row][chunk j] = global[row][j ^ (row&7)] (chunk = 16B).
// EPI: 0 = i8 out = clamp(round((v+bias[n])*scale)), split Cv/Cv2 at NS, pack4
//      4 = f32 out + bias[m] + residual
//      5 = fp8 e4m3 out = v + bias[m], pack4
template <int EPI>
__global__ void gemm_nt(const unsigned short* __restrict__ A, long long sAb,
                        const unsigned short* __restrict__ B, long long sBb,
                        void* __restrict__ Cv, void* __restrict__ Cv2, long long sCb,
                        const float* __restrict__ bias,
                        const float* __restrict__ resid, long long sRb,
                        int M, int N, int K, int Nst, int NS, float scale) {
    __shared__ __align__(16) unsigned short lA[128 * 64];
    __shared__ __align__(16) unsigned short lB[128 * 64];
    const int tid = threadIdx.x;
    const int wave = tid >> 6, lane = tid & 63;
    const int m0 = blockIdx.y * 128, n0 = blockIdx.x * 128, bz = blockIdx.z;
    const unsigned short* Ab = A + (size_t)bz * sAb;
    const unsigned short* Bb = B + (size_t)bz * sBb;

    floatx4 acc[4][4];
#pragma unroll
    for (int i = 0; i < 4; i++)
#pragma unroll
        for (int j = 0; j < 4; j++) acc[i][j] = (floatx4){0.f, 0.f, 0.f, 0.f};

    const int wm = (wave >> 1) * 64, wn = (wave & 1) * 64;
    const int quad = lane >> 4;   // 0..3
    const int lc = lane & 15;     // 0..15
    const int lc7 = lc & 7;

    const int nk = K >> 6;
    for (int kt = 0; kt < nk; ++kt) {
        const int kbase = kt * 64;
#pragma unroll
        for (int c = 0; c < 4; ++c) {
            int d = c * 256 + tid;
            int r = d >> 3;
            int kc = (d & 7) ^ (r & 7);
            const unsigned short* ga = Ab + (size_t)(m0 + r) * K + kbase + kc * 8;
            const unsigned short* gb = Bb + (size_t)(n0 + r) * K + kbase + kc * 8;
            __builtin_amdgcn_global_load_lds(
                (const __attribute__((address_space(1))) void*)ga,
                (__attribute__((address_space(3))) void*)&lA[(size_t)(c * 256 + wave * 64) * 8], 16, 0, 0);
            __builtin_amdgcn_global_load_lds(
                (const __attribute__((address_space(1))) void*)gb,
                (__attribute__((address_space(3))) void*)&lB[(size_t)(c * 256 + wave * 64) * 8], 16, 0, 0);
        }
        __syncthreads();
#pragma unroll
        for (int kk = 0; kk < 2; ++kk) {
            const int swz = ((kk * 4 + quad) ^ lc7) * 8;
            short8 af[4], bf[4];
#pragma unroll
            for (int i = 0; i < 4; i++)
                af[i] = *(const short8*)&lA[(size_t)(wm + i * 16 + lc) * 64 + swz];
#pragma unroll
            for (int j = 0; j < 4; j++)
                bf[j] = *(const short8*)&lB[(size_t)(wn + j * 16 + lc) * 64 + swz];
#pragma unroll
            for (int i = 0; i < 4; i++)
#pragma unroll
                for (int j = 0; j < 4; j++)
                    acc[i][j] = __builtin_amdgcn_mfma_f32_16x16x32_bf16(af[i], bf[j], acc[i][j], 0, 0, 0);
        }
        __syncthreads();
    }

    const int rowb = quad * 4;
#pragma unroll
    for (int i = 0; i < 4; i++) {
#pragma unroll
        for (int r = 0; r < 4; r++) {
            const int m = m0 + wm + i * 16 + rowb + r;
            if constexpr (EPI == 0) {
                float q[4];
#pragma unroll
                for (int j = 0; j < 4; j++) {
                    const int n = n0 + wn + j * 16 + lc;
                    q[j] = fminf(fmaxf((acc[i][j][r] + bias[n]) * scale, -127.f), 127.f);
                }
                const int col64 = n0 + wn;
                char* outp = (char*)((col64 < NS) ? Cv : Cv2);
                size_t idx = (size_t)bz * sCb + (size_t)m * Nst +
                             (col64 - ((col64 < NS) ? 0 : NS)) + lc * 4;
                *(unsigned*)(outp + idx) = pack_i8x4(q[0], q[1], q[2], q[3]);
            } else if constexpr (EPI == 5) {
                const float bm = bias[m];
                float q[4];
#pragma unroll
                for (int j = 0; j < 4; j++)
                    q[j] = fminf(fmaxf(acc[i][j][r] + bm, -448.f), 448.f);
                size_t idx = (size_t)bz * sCb + (size_t)m * Nst + n0 + wn + lc * 4;
                *(unsigned*)((char*)Cv + idx) = pack_fp8x4(q[0], q[1], q[2], q[3]);
            } else {
#pragma unroll
                for (int j = 0; j < 4; j++) {
                    const int n = n0 + wn + j * 16 + lc;
                    size_t idx = (size_t)bz * sCb + (size_t)m * Nst + n;
                    ((float*)Cv)[idx] = acc[i][j][r] + bias[m] +
                                        resid[(size_t)bz * sRb + (size_t)m * Nst + n];
                }
            }
        }
    }
}

// ---------------- i8 NT GEMM: P = e4m3(0.25*exp(qk*scale)), pack4, shuffle+atomic rowsum ----------------
// XCD-swizzled flat grid (4096 blocks). Separate lA/lB; no LDS reuse after the K-loop.
__global__ void gemm_i8_exp(const char* __restrict__ A, long long sAb,
                            const char* __restrict__ B, long long sBb,
                            char* __restrict__ Cv, long long sCb,
                            float* __restrict__ rowsum,
                            int M, int N, int K, float scale2) {
    __shared__ __align__(16) char lA[128 * 128];
    __shared__ __align__(16) char lB[128 * 128];
    const int tid = threadIdx.x;
    const int wave = tid >> 6, lane = tid & 63;
    const int flat = blockIdx.x;
    const int xcd = flat & 7;
    const int idx = flat >> 3;          // 0..511
    const int bz = idx >> 7;            // 0..3
    const int r2 = idx & 127;
    const int m0 = (xcd * 4 + (r2 >> 5)) * 128;
    const int n0 = (r2 & 31) * 128;
    const char* Ab = A + (size_t)bz * sAb;
    const char* Bb = B + (size_t)bz * sBb;

    i32x4 acc[4][4];
#pragma unroll
    for (int i = 0; i < 4; i++)
#pragma unroll
        for (int j = 0; j < 4; j++) acc[i][j] = (i32x4){0, 0, 0, 0};

    const int wm = (wave >> 1) * 64, wn = (wave & 1) * 64;
    const int quad = lane >> 4;
    const int lc = lane & 15;
    const int lc7 = lc & 7;

    const int nk = K >> 7;
    for (int kt = 0; kt < nk; ++kt) {
        const int kbase = kt * 128;
#pragma unroll
        for (int c = 0; c < 4; ++c) {
            int d = c * 256 + tid;
            int r = d >> 3;
            int kc = (d & 7) ^ (r & 7);
            const char* ga = Ab + (size_t)(m0 + r) * K + kbase + kc * 16;
            const char* gb = Bb + (size_t)(n0 + r) * K + kbase + kc * 16;
            __builtin_amdgcn_global_load_lds(
                (const __attribute__((address_space(1))) void*)ga,
                (__attribute__((address_space(3))) void*)&lA[(size_t)(c * 256 + wave * 64) * 16], 16, 0, 0);
            __builtin_amdgcn_global_load_lds(
                (const __attribute__((address_space(1))) void*)gb,
                (__attribute__((address_space(3))) void*)&lB[(size_t)(c * 256 + wave * 64) * 16], 16, 0, 0);
        }
        __syncthreads();
#pragma unroll
        for (int kk = 0; kk < 2; ++kk) {
            const int swz = ((kk * 4 + quad) ^ lc7) * 16;
            i32x4 af[4], bf[4];
#pragma unroll
            for (int i = 0; i < 4; i++)
                af[i] = *(const i32x4*)&lA[(size_t)(wm + i * 16 + lc) * 128 + swz];
#pragma unroll
            for (int j = 0; j < 4; j++)
                bf[j] = *(const i32x4*)&lB[(size_t)(wn + j * 16 + lc) * 128 + swz];
#pragma unroll
            for (int i = 0; i < 4; i++)
#pragma unroll
                for (int j = 0; j < 4; j++)
                    acc[i][j] = __builtin_amdgcn_mfma_i32_16x16x64_i8(af[i], bf[j], acc[i][j], 0, 0, 0);
        }
        __syncthreads();
    }

    const int rowb = quad * 4;
#pragma unroll
    for (int i = 0; i < 4; i++) {
#pragma unroll
        for (int r = 0; r < 4; r++) {
            const int m = m0 + wm + i * 16 + rowb + r;
            float e[4];
            float rsacc = 0.f;
#pragma unroll
            for (int j = 0; j < 4; j++) {
                e[j] = fminf(exp2f(fmaf((float)acc[i][j][r], scale2, -2.0f)), 448.f);
                rsacc += e[j];
            }
            size_t oidx = (size_t)bz * sCb + (size_t)m * N + n0 + wn + lc * 4;
            *(unsigned*)(Cv + oidx) = pack_fp8x4(e[0], e[1], e[2], e[3]);
            rsacc += __shfl_xor(rsacc, 1);
            rsacc += __shfl_xor(rsacc, 2);
            rsacc += __shfl_xor(rsacc, 4);
            rsacc += __shfl_xor(rsacc, 8);
            if (lc == 0) atomicAdd(&rowsum[(size_t)bz * M + m], rsacc);
        }
    }
}

// ---------------- fp8 NT GEMM: O_t[q][d] = (sum_k P[q][k]*V[d][k]) / rowsum[q] ----------------
// bf16 out in pack4-permuted d layout (consumer proj uses permuted wp). XCD-swizzled.
__global__ void gemm_fp8_o(const char* __restrict__ A, long long sAb,
                           const char* __restrict__ B, long long sBb,
                           unsigned short* __restrict__ Cv, long long sCb,
                           const float* __restrict__ rowsum,
                           int M, int N, int K) {
    __shared__ __align__(16) char lA[128 * 128];
    __shared__ __align__(16) char lB[128 * 128];
    const int tid = threadIdx.x;
    const int wave = tid >> 6, lane = tid & 63;
    int flat = blockIdx.x;
    int xcd = flat & 7, idx = flat >> 3;
    int nt = idx & 3, si = idx >> 2;
    int stripe = xcd * 16 + si;
    const int m0 = (stripe & 31) * 128;
    const int n0 = nt * 128;
    const int bz = stripe >> 5;
    const char* Ab = A + (size_t)bz * sAb;
    const char* Bb = B + (size_t)bz * sBb;

    floatx4 acc[4][4];
#pragma unroll
    for (int i = 0; i < 4; i++)
#pragma unroll
        for (int j = 0; j < 4; j++) acc[i][j] = (floatx4){0.f, 0.f, 0.f, 0.f};

    const int wm = (wave >> 1) * 64, wn = (wave & 1) * 64;
    const int quad = lane >> 4;
    const int lc = lane & 15;
    const int lc7 = lc & 7;
    const int half = quad & 1;

    const int nk = K >> 7;
    for (int kt = 0; kt < nk; ++kt) {
        const int kbase = kt * 128;
#pragma unroll
        for (int c = 0; c < 4; ++c) {
            int d = c * 256 + tid;
            int r = d >> 3;
            int kc = (d & 7) ^ (r & 7);
            const char* ga = Ab + (size_t)(m0 + r) * K + kbase + kc * 16;
            const char* gb = Bb + (size_t)(n0 + r) * K + kbase + kc * 16;
            __builtin_amdgcn_global_load_lds(
                (const __attribute__((address_space(1))) void*)ga,
                (__attribute__((address_space(3))) void*)&lA[(size_t)(c * 256 + wave * 64) * 16], 16, 0, 0);
            __builtin_amdgcn_global_load_lds(
                (const __attribute__((address_space(1))) void*)gb,
                (__attribute__((address_space(3))) void*)&lB[(size_t)(c * 256 + wave * 64) * 16], 16, 0, 0);
        }
        __syncthreads();
#pragma unroll
        for (int t = 0; t < 4; ++t) {
            const int swz = ((2 * t + (quad >> 1)) ^ lc7) * 16;
            long a8[4], b8[4];
#pragma unroll
            for (int i = 0; i < 4; i++) {
                longx2 v = *(const longx2*)&lA[(size_t)(wm + i * 16 + lc) * 128 + swz];
                a8[i] = v[half];
            }
#pragma unroll
            for (int j = 0; j < 4; j++) {
                longx2 v = *(const longx2*)&lB[(size_t)(wn + j * 16 + lc) * 128 + swz];
                b8[j] = v[half];
            }
#pragma unroll
            for (int i = 0; i < 4; i++)
#pragma unroll
                for (int j = 0; j < 4; j++)
                    acc[i][j] = __builtin_amdgcn_mfma_f32_16x16x32_fp8_fp8(a8[i], b8[j], acc[i][j], 0, 0, 0);
        }
        __syncthreads();
    }

    const int rowb = quad * 4;
#pragma unroll
    for (int i = 0; i < 4; i++) {
#pragma unroll
        for (int r = 0; r < 4; r++) {
            const int m = m0 + wm + i * 16 + rowb + r;
            const float pscale = 1.f / rowsum[(size_t)bz * M + m];
            unsigned short h[4];
#pragma unroll
            for (int j = 0; j < 4; j++) h[j] = f2bs(acc[i][j][r] * pscale);
            uint2 u;
            u.x = (unsigned)h[0] | ((unsigned)h[1] << 16);
            u.y = (unsigned)h[2] | ((unsigned)h[3] << 16);
            *(uint2*)&Cv[(size_t)bz * sCb + (size_t)m * N + n0 + wn + lc * 4] = u;
        }
    }
}

extern "C" void kernel_launch(void* const* d_in, const int* in_sizes, int n_in,
                              void* d_out, int out_size, void* d_ws, size_t ws_size,
                              hipStream_t stream) {
    (void)in_sizes; (void)n_in; (void)out_size; (void)ws_size;
    const float* x   = (const float*)d_in[0];
    const float* gnw = (const float*)d_in[1];
    const float* gnb = (const float*)d_in[2];
    const float* qw  = (const float*)d_in[3];
    const float* qb  = (const float*)d_in[4];
    const float* kw  = (const float*)d_in[5];
    const float* kb  = (const float*)d_in[6];
    const float* vw  = (const float*)d_in[7];
    const float* vb  = (const float*)d_in[8];
    const float* pw  = (const float*)d_in[9];
    const float* pb  = (const float*)d_in[10];
    float* out = (float*)d_out;

    char* ws = (char*)d_ws;
    unsigned short* h_t = (unsigned short*)(ws);
    unsigned short* o_t = h_t;  // alias: h_t dead after v GEMM
    char* q_i8 = (char*)(ws + (16ull << 20));
    char* k_i8 = (char*)(ws + (32ull << 20));
    char* v_f8 = (char*)(ws + (48ull << 20));
    unsigned short* wqkb = (unsigned short*)(ws + (64ull << 20));  // [qw;kw] 1024x512
    unsigned short* wvb = (unsigned short*)(ws + (65ull << 20));
    unsigned short* wpb = wvb + 262144;  // pack4-permuted k-cols
    float* stats  = (float*)(ws + (66ull << 20));
    float* rowsum = (float*)(ws + (66ull << 20) + 65536);
    float* biasqk = (float*)(ws + (66ull << 20) + 131072);
    char* p_f8 = (char*)(ws + (67ull << 20));

    const long long sP  = 2097152;   // 4096*512 elements per batch
    const long long sS  = 16777216;  // 4096*4096 bytes per batch (fp8 P)
    const int BIG = 1 << 30;
    const float QS = 16.f;
    const float SC = 0.044194173824159216f / (QS * QS);
    const float LOG2E = 1.4426950408889634f;

    setup_kernel<<<1025, 256, 0, stream>>>(qw, kw, vw, pw, qb, kb, wqkb, wvb, wpb, biasqk, rowsum);
    gn_stats_kernel<<<128, 256, 0, stream>>>(x, stats);
    gn_apply_kernel<<<dim3(64, 8, 4), 256, 0, stream>>>(x, stats, gnw, gnb, h_t);
    // merged q|k: M=4096(p), N=1024(o), K=512(c); i8 pack4 outputs split at NS=512
    gemm_nt<0><<<dim3(8, 32, 4), 256, 0, stream>>>(h_t, sP, wqkb, 0, q_i8, k_i8, sP, biasqk,
                                                   nullptr, 0, 4096, 1024, 512, 512, 512, QS);
    // v[d][p] -> e4m3 pack4: M=512(d), N=4096(p), K=512(c)
    gemm_nt<5><<<dim3(32, 4, 4), 256, 0, stream>>>(wvb, 0, h_t, sP, v_f8, v_f8, sP, vb,
                                                   nullptr, 0, 512, 4096, 512, 4096, BIG, 1.f);
    // P[q][k] = e4m3(0.25*exp(qk*SC)) pack4, shuffle+atomic rowsums, XCD-swizzled flat grid
    gemm_i8_exp<<<dim3(4096, 1, 1), 256, 0, stream>>>(q_i8, sP, k_i8, sP, p_f8, sS, rowsum,
                                                      4096, 4096, 512, SC * LOG2E);
    // O_t[q][d] = (P . v^T)/rowsum: fp8 MFMA, pack4-permuted bf16 out, XCD-swizzled
    gemm_fp8_o<<<dim3(512, 1, 1), 256, 0, stream>>>(p_f8, sS, v_f8, sP, o_t, sP, rowsum,
                                                    4096, 512, 4096);
    // y = x + wp~ . O_t^T + pb: M=512(o), N=4096(p), K=512(d, permutation cancels)
    gemm_nt<4><<<dim3(32, 4, 4), 256, 0, stream>>>(wpb, 0, o_t, sP, (void*)out, nullptr, sP, pb,
                                                   x, sP, 512, 4096, 512, 4096, BIG, 1.f);
}

// Round 11
// 309.821 us; speedup vs baseline: 1.0488x; 1.0142x over previous
//
#include <hip/hip_runtime.h>

#define DEV __device__ __forceinline__

typedef __attribute__((ext_vector_type(8))) short short8;
typedef __attribute__((ext_vector_type(4))) float floatx4;
typedef __attribute__((ext_vector_type(4))) int i32x4;
typedef __attribute__((ext_vector_type(2))) long longx2;

DEV unsigned short f2bs(float x) {
    unsigned u = __float_as_uint(x);
    unsigned r = (u + 0x7fffu + ((u >> 16) & 1u)) >> 16;
    return (unsigned short)r;
}

// f32 -> OCP e4m3fn. Caller pre-clamps to [-448, 448]. Fallback: branchless, FTZ below 2^-6.
DEV unsigned char f2fp8(float x) {
#if __has_builtin(__builtin_amdgcn_cvt_pk_fp8_f32)
    int pk = __builtin_amdgcn_cvt_pk_fp8_f32(x, 0.f, 0, false);
    return (unsigned char)(pk & 0xff);
#else
    unsigned u = __float_as_uint(x);
    unsigned s = (u >> 24) & 0x80;
    unsigned a = u & 0x7fffffff;
    unsigned um = a + 0x7ffffu + ((a >> 20) & 1u);
    unsigned r = (a >= 0x3c800000u) ? ((um >> 20) - 0x3C0u) : 0u;
    return (unsigned char)(r | s);
#endif
}

DEV unsigned pack_fp8x4(float v0, float v1, float v2, float v3) {
#if __has_builtin(__builtin_amdgcn_cvt_pk_fp8_f32)
    unsigned pk = (unsigned)__builtin_amdgcn_cvt_pk_fp8_f32(v0, v1, 0, false);
    pk = (unsigned)__builtin_amdgcn_cvt_pk_fp8_f32(v2, v3, (int)pk, true);
    return pk;
#else
    return (unsigned)f2fp8(v0) | ((unsigned)f2fp8(v1) << 8) |
           ((unsigned)f2fp8(v2) << 16) | ((unsigned)f2fp8(v3) << 24);
#endif
}

DEV unsigned pack_i8x4(float v0, float v1, float v2, float v3) {
    unsigned b0 = (unsigned)((int)rintf(v0)) & 255u;
    unsigned b1 = (unsigned)((int)rintf(v1)) & 255u;
    unsigned b2 = (unsigned)((int)rintf(v2)) & 255u;
    unsigned b3 = (unsigned)((int)rintf(v3)) & 255u;
    return b0 | (b1 << 8) | (b2 << 16) | (b3 << 24);
}

// ---------------- merged pre-pass: setup (blocks 0..1024) + gn_stats (1025..1152) ----------------
// wp's k-columns get the pack4 permutation (col 16j+lc -> 4lc+j within each 64-block)
// to match o_t's permuted store layout in gemm_fp8_o.
__global__ void pre_kernel(const float* __restrict__ x,
                           const float* __restrict__ qw, const float* __restrict__ kw,
                           const float* __restrict__ vw, const float* __restrict__ pw,
                           const float* __restrict__ qb, const float* __restrict__ kb,
                           unsigned short* __restrict__ wqkb, unsigned short* __restrict__ wvb,
                           unsigned short* __restrict__ wpb,
                           float* __restrict__ biasqk, float* __restrict__ rowsum,
                           float* __restrict__ stats) {
    int b = blockIdx.x, tid = threadIdx.x;
    if (b < 768) {
        const float* src = (b < 256) ? qw : (b < 512) ? kw : vw;
        unsigned short* dst = (b < 256) ? wqkb : (b < 512) ? (wqkb + 262144) : wvb;
        int off = (b & 255) * 256 + tid;
        float4 v = ((const float4*)src)[off];
        ushort4 o;
        o.x = f2bs(v.x); o.y = f2bs(v.y); o.z = f2bs(v.z); o.w = f2bs(v.w);
        ((ushort4*)dst)[off] = o;
    } else if (b < 1024) {
        int off = (b - 768) * 256 + tid;
        int row = off >> 7, c4 = (off & 127) * 4;
        float4 v = ((const float4*)pw)[off];
        float vv[4] = {v.x, v.y, v.z, v.w};
#pragma unroll
        for (int e = 0; e < 4; ++e) {
            int c = c4 + e;
            int j = (c >> 4) & 3, lc = c & 15;
            int cp = (c & ~63) | (lc * 4 + j);
            wpb[row * 512 + cp] = f2bs(vv[e]);
        }
    } else if (b == 1024) {
        biasqk[tid]       = qb[tid];
        biasqk[256 + tid] = qb[256 + tid];
        biasqk[512 + tid] = kb[tid];
        biasqk[768 + tid] = kb[256 + tid];
        float4 z = {0.f, 0.f, 0.f, 0.f};
#pragma unroll
        for (int k = 0; k < 16; ++k) ((float4*)rowsum)[k * 256 + tid] = z;
    } else {
        int bg = b - 1025;  // 0..127
        const float4* p = (const float4*)(x + (size_t)bg * 65536);
        float s = 0.f, ss = 0.f;
        for (int i = tid; i < 16384; i += 256) {
            float4 v = p[i];
            s += v.x + v.y + v.z + v.w;
            ss += v.x * v.x + v.y * v.y + v.z * v.z + v.w * v.w;
        }
        for (int off = 32; off; off >>= 1) { s += __shfl_down(s, off); ss += __shfl_down(ss, off); }
        __shared__ float rs[4], rss[4];
        int wave = tid >> 6, lane = tid & 63;
        if (lane == 0) { rs[wave] = s; rss[wave] = ss; }
        __syncthreads();
        if (tid == 0) {
            float S = rs[0] + rs[1] + rs[2] + rs[3];
            float SS = rss[0] + rss[1] + rss[2] + rss[3];
            float mean = S * (1.f / 65536.f);
            float var = SS * (1.f / 65536.f) - mean * mean;
            stats[bg * 2] = mean;
            stats[bg * 2 + 1] = rsqrtf(var + 1e-5f);
        }
    }
}

// ------------- GN apply + transpose: x[b][c][p] fp32 -> h_t[b][p][c] bf16 -------------
__global__ void gn_apply_kernel(const float* __restrict__ x, const float* __restrict__ stats,
                                const float* __restrict__ gw, const float* __restrict__ gb,
                                unsigned short* __restrict__ ht) {
    __shared__ __align__(16) unsigned short t[64][72];
    int b = blockIdx.z, c0 = blockIdx.y * 64, p0 = blockIdx.x * 64;
    int tid = threadIdx.x;
    const float* xb = x + ((size_t)b * 512 + c0) * 4096 + p0;
#pragma unroll
    for (int pass = 0; pass < 4; ++pass) {
        int cl = pass * 16 + (tid >> 4);
        int pq = (tid & 15) * 4;
        float4 v = *(const float4*)(xb + (size_t)cl * 4096 + pq);
        int c = c0 + cl, g = c >> 4;
        float mean = stats[(b * 32 + g) * 2], rstd = stats[(b * 32 + g) * 2 + 1];
        float sw = gw[c] * rstd;
        float sb = gb[c] - mean * sw;
        t[pq + 0][cl] = f2bs(v.x * sw + sb);
        t[pq + 1][cl] = f2bs(v.y * sw + sb);
        t[pq + 2][cl] = f2bs(v.z * sw + sb);
        t[pq + 3][cl] = f2bs(v.w * sw + sb);
    }
    __syncthreads();
    unsigned short* hb = ht + ((size_t)b * 4096 + p0) * 512 + c0;
#pragma unroll
    for (int pass = 0; pass < 2; ++pass) {
        int pl = pass * 32 + (tid >> 3);
        int c8 = (tid & 7) * 8;
        *(uint4*)(hb + (size_t)pl * 512 + c8) = *(const uint4*)&t[pl][c8];
    }
}

// ---------------- merged qkv NT GEMM (K=512, bf16): blocks 0..1023 = q|k, 1024..1535 = v ----------------
// q|k: A=h_t[b], B=wqk, M=4096, N=1024 -> i8 pack4 split at 512 (scale QS, bias[n])
// v:   A=wv,     B=h_t[b], M=512, N=4096 -> fp8 e4m3 pack4 (bias[m])
__global__ void gemm_qkv(const unsigned short* __restrict__ h_t, long long sP,
                         const unsigned short* __restrict__ wqkb,
                         const unsigned short* __restrict__ wvb,
                         char* __restrict__ q_i8, char* __restrict__ k_i8,
                         char* __restrict__ v_f8,
                         const float* __restrict__ biasqk, const float* __restrict__ vb,
                         float qs) {
    __shared__ __align__(16) unsigned short lA[128 * 64];
    __shared__ __align__(16) unsigned short lB[128 * 64];
    const int tid = threadIdx.x;
    const int wave = tid >> 6, lane = tid & 63;
    const int flat = blockIdx.x;
    const bool isqk = flat < 1024;
    int m0, n0, bz;
    const unsigned short *Ab, *Bb;
    if (isqk) {
        m0 = ((flat >> 3) & 31) * 128;
        n0 = (flat & 7) * 128;
        bz = flat >> 8;
        Ab = h_t + (size_t)bz * sP;
        Bb = wqkb;
    } else {
        const int g = flat - 1024;
        m0 = ((g >> 5) & 3) * 128;
        n0 = (g & 31) * 128;
        bz = g >> 7;
        Ab = wvb;
        Bb = h_t + (size_t)bz * sP;
    }

    floatx4 acc[4][4];
#pragma unroll
    for (int i = 0; i < 4; i++)
#pragma unroll
        for (int j = 0; j < 4; j++) acc[i][j] = (floatx4){0.f, 0.f, 0.f, 0.f};

    const int wm = (wave >> 1) * 64, wn = (wave & 1) * 64;
    const int quad = lane >> 4;
    const int lc = lane & 15;
    const int lc7 = lc & 7;

    for (int kt = 0; kt < 8; ++kt) {
        const int kbase = kt * 64;
#pragma unroll
        for (int c = 0; c < 4; ++c) {
            int d = c * 256 + tid;
            int r = d >> 3;
            int kc = (d & 7) ^ (r & 7);
            const unsigned short* ga = Ab + (size_t)(m0 + r) * 512 + kbase + kc * 8;
            const unsigned short* gb = Bb + (size_t)(n0 + r) * 512 + kbase + kc * 8;
            __builtin_amdgcn_global_load_lds(
                (const __attribute__((address_space(1))) void*)ga,
                (__attribute__((address_space(3))) void*)&lA[(size_t)(c * 256 + wave * 64) * 8], 16, 0, 0);
            __builtin_amdgcn_global_load_lds(
                (const __attribute__((address_space(1))) void*)gb,
                (__attribute__((address_space(3))) void*)&lB[(size_t)(c * 256 + wave * 64) * 8], 16, 0, 0);
        }
        __syncthreads();
#pragma unroll
        for (int kk = 0; kk < 2; ++kk) {
            const int swz = ((kk * 4 + quad) ^ lc7) * 8;
            short8 af[4], bf[4];
#pragma unroll
            for (int i = 0; i < 4; i++)
                af[i] = *(const short8*)&lA[(size_t)(wm + i * 16 + lc) * 64 + swz];
#pragma unroll
            for (int j = 0; j < 4; j++)
                bf[j] = *(const short8*)&lB[(size_t)(wn + j * 16 + lc) * 64 + swz];
#pragma unroll
            for (int i = 0; i < 4; i++)
#pragma unroll
                for (int j = 0; j < 4; j++)
                    acc[i][j] = __builtin_amdgcn_mfma_f32_16x16x32_bf16(af[i], bf[j], acc[i][j], 0, 0, 0);
        }
        __syncthreads();
    }

    const int rowb = quad * 4;
    if (isqk) {
#pragma unroll
        for (int i = 0; i < 4; i++) {
#pragma unroll
            for (int r = 0; r < 4; r++) {
                const int m = m0 + wm + i * 16 + rowb + r;
                float q[4];
#pragma unroll
                for (int j = 0; j < 4; j++) {
                    const int n = n0 + wn + j * 16 + lc;
                    q[j] = fminf(fmaxf((acc[i][j][r] + biasqk[n]) * qs, -127.f), 127.f);
                }
                const int col64 = n0 + wn;
                char* outp = (col64 < 512) ? q_i8 : k_i8;
                size_t idx = (size_t)bz * sP + (size_t)m * 512 +
                             (col64 - ((col64 < 512) ? 0 : 512)) + lc * 4;
                *(unsigned*)(outp + idx) = pack_i8x4(q[0], q[1], q[2], q[3]);
            }
        }
    } else {
#pragma unroll
        for (int i = 0; i < 4; i++) {
#pragma unroll
            for (int r = 0; r < 4; r++) {
                const int m = m0 + wm + i * 16 + rowb + r;
                const float bm = vb[m];
                float q[4];
#pragma unroll
                for (int j = 0; j < 4; j++)
                    q[j] = fminf(fmaxf(acc[i][j][r] + bm, -448.f), 448.f);
                size_t idx = (size_t)bz * sP + (size_t)m * 4096 + n0 + wn + lc * 4;
                *(unsigned*)(v_f8 + idx) = pack_fp8x4(q[0], q[1], q[2], q[3]);
            }
        }
    }
}

// ---------------- NT GEMM, bf16, fp32-out epilogue (proj): y = A.B^T + bias[m] + resid ----------------
__global__ void gemm_proj(const unsigned short* __restrict__ A,
                          const unsigned short* __restrict__ B, long long sBb,
                          float* __restrict__ Cv, long long sCb,
                          const float* __restrict__ bias,
                          const float* __restrict__ resid, long long sRb,
                          int M, int N, int K) {
    __shared__ __align__(16) unsigned short lA[128 * 64];
    __shared__ __align__(16) unsigned short lB[128 * 64];
    const int tid = threadIdx.x;
    const int wave = tid >> 6, lane = tid & 63;
    const int m0 = blockIdx.y * 128, n0 = blockIdx.x * 128, bz = blockIdx.z;
    const unsigned short* Ab = A;
    const unsigned short* Bb = B + (size_t)bz * sBb;

    floatx4 acc[4][4];
#pragma unroll
    for (int i = 0; i < 4; i++)
#pragma unroll
        for (int j = 0; j < 4; j++) acc[i][j] = (floatx4){0.f, 0.f, 0.f, 0.f};

    const int wm = (wave >> 1) * 64, wn = (wave & 1) * 64;
    const int quad = lane >> 4;
    const int lc = lane & 15;
    const int lc7 = lc & 7;

    const int nk = K >> 6;
    for (int kt = 0; kt < nk; ++kt) {
        const int kbase = kt * 64;
#pragma unroll
        for (int c = 0; c < 4; ++c) {
            int d = c * 256 + tid;
            int r = d >> 3;
            int kc = (d & 7) ^ (r & 7);
            const unsigned short* ga = Ab + (size_t)(m0 + r) * K + kbase + kc * 8;
            const unsigned short* gb = Bb + (size_t)(n0 + r) * K + kbase + kc * 8;
            __builtin_amdgcn_global_load_lds(
                (const __attribute__((address_space(1))) void*)ga,
                (__attribute__((address_space(3))) void*)&lA[(size_t)(c * 256 + wave * 64) * 8], 16, 0, 0);
            __builtin_amdgcn_global_load_lds(
                (const __attribute__((address_space(1))) void*)gb,
                (__attribute__((address_space(3))) void*)&lB[(size_t)(c * 256 + wave * 64) * 8], 16, 0, 0);
        }
        __syncthreads();
#pragma unroll
        for (int kk = 0; kk < 2; ++kk) {
            const int swz = ((kk * 4 + quad) ^ lc7) * 8;
            short8 af[4], bf[4];
#pragma unroll
            for (int i = 0; i < 4; i++)
                af[i] = *(const short8*)&lA[(size_t)(wm + i * 16 + lc) * 64 + swz];
#pragma unroll
            for (int j = 0; j < 4; j++)
                bf[j] = *(const short8*)&lB[(size_t)(wn + j * 16 + lc) * 64 + swz];
#pragma unroll
            for (int i = 0; i < 4; i++)
#pragma unroll
                for (int j = 0; j < 4; j++)
                    acc[i][j] = __builtin_amdgcn_mfma_f32_16x16x32_bf16(af[i], bf[j], acc[i][j], 0, 0, 0);
        }
        __syncthreads();
    }

    const int rowb = quad * 4;
#pragma unroll
    for (int i = 0; i < 4; i++) {
#pragma unroll
        for (int r = 0; r < 4; r++) {
            const int m = m0 + wm + i * 16 + rowb + r;
            const float bm = bias[m];
#pragma unroll
            for (int j = 0; j < 4; j++) {
                const int n = n0 + wn + j * 16 + lc;
                size_t idx = (size_t)bz * sCb + (size_t)m * N + n;
                Cv[idx] = acc[i][j][r] + bm + resid[(size_t)bz * sRb + (size_t)m * N + n];
            }
        }
    }
}

// ---------------- i8 NT GEMM: P = e4m3(0.25*exp(qk*scale)), pack4, shuffle+atomic rowsum ----------------
// Standard dim3(32,32,4) grid (measured faster than XCD swizzle for this kernel — r7 vs r9).
__global__ void gemm_i8_exp(const char* __restrict__ A, long long sAb,
                            const char* __restrict__ B, long long sBb,
                            char* __restrict__ Cv, long long sCb,
                            float* __restrict__ rowsum,
                            int M, int N, int K, float scale2) {
    __shared__ __align__(16) char lA[128 * 128];
    __shared__ __align__(16) char lB[128 * 128];
    const int tid = threadIdx.x;
    const int wave = tid >> 6, lane = tid & 63;
    const int m0 = blockIdx.y * 128, n0 = blockIdx.x * 128, bz = blockIdx.z;
    const char* Ab = A + (size_t)bz * sAb;
    const char* Bb = B + (size_t)bz * sBb;

    i32x4 acc[4][4];
#pragma unroll
    for (int i = 0; i < 4; i++)
#pragma unroll
        for (int j = 0; j < 4; j++) acc[i][j] = (i32x4){0, 0, 0, 0};

    const int wm = (wave >> 1) * 64, wn = (wave & 1) * 64;
    const int quad = lane >> 4;
    const int lc = lane & 15;
    const int lc7 = lc & 7;

    const int nk = K >> 7;
    for (int kt = 0; kt < nk; ++kt) {
        const int kbase = kt * 128;
#pragma unroll
        for (int c = 0; c < 4; ++c) {
            int d = c * 256 + tid;
            int r = d >> 3;
            int kc = (d & 7) ^ (r & 7);
            const char* ga = Ab + (size_t)(m0 + r) * K + kbase + kc * 16;
            const char* gb = Bb + (size_t)(n0 + r) * K + kbase + kc * 16;
            __builtin_amdgcn_global_load_lds(
                (const __attribute__((address_space(1))) void*)ga,
                (__attribute__((address_space(3))) void*)&lA[(size_t)(c * 256 + wave * 64) * 16], 16, 0, 0);
            __builtin_amdgcn_global_load_lds(
                (const __attribute__((address_space(1))) void*)gb,
                (__attribute__((address_space(3))) void*)&lB[(size_t)(c * 256 + wave * 64) * 16], 16, 0, 0);
        }
        __syncthreads();
#pragma unroll
        for (int kk = 0; kk < 2; ++kk) {
            const int swz = ((kk * 4 + quad) ^ lc7) * 16;
            i32x4 af[4], bf[4];
#pragma unroll
            for (int i = 0; i < 4; i++)
                af[i] = *(const i32x4*)&lA[(size_t)(wm + i * 16 + lc) * 128 + swz];
#pragma unroll
            for (int j = 0; j < 4; j++)
                bf[j] = *(const i32x4*)&lB[(size_t)(wn + j * 16 + lc) * 128 + swz];
#pragma unroll
            for (int i = 0; i < 4; i++)
#pragma unroll
                for (int j = 0; j < 4; j++)
                    acc[i][j] = __builtin_amdgcn_mfma_i32_16x16x64_i8(af[i], bf[j], acc[i][j], 0, 0, 0);
        }
        __syncthreads();
    }

    const int rowb = quad * 4;
#pragma unroll
    for (int i = 0; i < 4; i++) {
#pragma unroll
        for (int r = 0; r < 4; r++) {
            const int m = m0 + wm + i * 16 + rowb + r;
            float e[4];
            float rsacc = 0.f;
#pragma unroll
            for (int j = 0; j < 4; j++) {
                e[j] = fminf(exp2f(fmaf((float)acc[i][j][r], scale2, -2.0f)), 448.f);
                rsacc += e[j];
            }
            size_t oidx = (size_t)bz * sCb + (size_t)m * N + n0 + wn + lc * 4;
            *(unsigned*)(Cv + oidx) = pack_fp8x4(e[0], e[1], e[2], e[3]);
            rsacc += __shfl_xor(rsacc, 1);
            rsacc += __shfl_xor(rsacc, 2);
            rsacc += __shfl_xor(rsacc, 4);
            rsacc += __shfl_xor(rsacc, 8);
            if (lc == 0) atomicAdd(&rowsum[(size_t)bz * M + m], rsacc);
        }
    }
}

// ---------------- fp8 NT GEMM: O_t[q][d] = (sum_k P[q][k]*V[d][k]) / rowsum[q] ----------------
// bf16 out in pack4-permuted d layout (consumer proj uses permuted wp). XCD-swizzled.
__global__ void gemm_fp8_o(const char* __restrict__ A, long long sAb,
                           const char* __restrict__ B, long long sBb,
                           unsigned short* __restrict__ Cv, long long sCb,
                           const float* __restrict__ rowsum,
                           int M, int N, int K) {
    __shared__ __align__(16) char lA[128 * 128];
    __shared__ __align__(16) char lB[128 * 128];
    const int tid = threadIdx.x;
    const int wave = tid >> 6, lane = tid & 63;
    int flat = blockIdx.x;
    int xcd = flat & 7, idx = flat >> 3;
    int nt = idx & 3, si = idx >> 2;
    int stripe = xcd * 16 + si;
    const int m0 = (stripe & 31) * 128;
    const int n0 = nt * 128;
    const int bz = stripe >> 5;
    const char* Ab = A + (size_t)bz * sAb;
    const char* Bb = B + (size_t)bz * sBb;

    floatx4 acc[4][4];
#pragma unroll
    for (int i = 0; i < 4; i++)
#pragma unroll
        for (int j = 0; j < 4; j++) acc[i][j] = (floatx4){0.f, 0.f, 0.f, 0.f};

    const int wm = (wave >> 1) * 64, wn = (wave & 1) * 64;
    const int quad = lane >> 4;
    const int lc = lane & 15;
    const int lc7 = lc & 7;
    const int half = quad & 1;

    const int nk = K >> 7;
    for (int kt = 0; kt < nk; ++kt) {
        const int kbase = kt * 128;
#pragma unroll
        for (int c = 0; c < 4; ++c) {
            int d = c * 256 + tid;
            int r = d >> 3;
            int kc = (d & 7) ^ (r & 7);
            const char* ga = Ab + (size_t)(m0 + r) * K + kbase + kc * 16;
            const char* gb = Bb + (size_t)(n0 + r) * K + kbase + kc * 16;
            __builtin_amdgcn_global_load_lds(
                (const __attribute__((address_space(1))) void*)ga,
                (__attribute__((address_space(3))) void*)&lA[(size_t)(c * 256 + wave * 64) * 16], 16, 0, 0);
            __builtin_amdgcn_global_load_lds(
                (const __attribute__((address_space(1))) void*)gb,
                (__attribute__((address_space(3))) void*)&lB[(size_t)(c * 256 + wave * 64) * 16], 16, 0, 0);
        }
        __syncthreads();
#pragma unroll
        for (int t = 0; t < 4; ++t) {
            const int swz = ((2 * t + (quad >> 1)) ^ lc7) * 16;
            long a8[4], b8[4];
#pragma unroll
            for (int i = 0; i < 4; i++) {
                longx2 v = *(const longx2*)&lA[(size_t)(wm + i * 16 + lc) * 128 + swz];
                a8[i] = v[half];
            }
#pragma unroll
            for (int j = 0; j < 4; j++) {
                longx2 v = *(const longx2*)&lB[(size_t)(wn + j * 16 + lc) * 128 + swz];
                b8[j] = v[half];
            }
#pragma unroll
            for (int i = 0; i < 4; i++)
#pragma unroll
                for (int j = 0; j < 4; j++)
                    acc[i][j] = __builtin_amdgcn_mfma_f32_16x16x32_fp8_fp8(a8[i], b8[j], acc[i][j], 0, 0, 0);
        }
        __syncthreads();
    }

    const int rowb = quad * 4;
#pragma unroll
    for (int i = 0; i < 4; i++) {
#pragma unroll
        for (int r = 0; r < 4; r++) {
            const int m = m0 + wm + i * 16 + rowb + r;
            const float pscale = 1.f / rowsum[(size_t)bz * M + m];
            unsigned short h[4];
#pragma unroll
            for (int j = 0; j < 4; j++) h[j] = f2bs(acc[i][j][r] * pscale);
            uint2 u;
            u.x = (unsigned)h[0] | ((unsigned)h[1] << 16);
            u.y = (unsigned)h[2] | ((unsigned)h[3] << 16);
            *(uint2*)&Cv[(size_t)bz * sCb + (size_t)m * N + n0 + wn + lc * 4] = u;
        }
    }
}

extern "C" void kernel_launch(void* const* d_in, const int* in_sizes, int n_in,
                              void* d_out, int out_size, void* d_ws, size_t ws_size,
                              hipStream_t stream) {
    (void)in_sizes; (void)n_in; (void)out_size; (void)ws_size;
    const float* x   = (const float*)d_in[0];
    const float* gnw = (const float*)d_in[1];
    const float* gnb = (const float*)d_in[2];
    const float* qw  = (const float*)d_in[3];
    const float* qb  = (const float*)d_in[4];
    const float* kw  = (const float*)d_in[5];
    const float* kb  = (const float*)d_in[6];
    const float* vw  = (const float*)d_in[7];
    const float* vb  = (const float*)d_in[8];
    const float* pw  = (const float*)d_in[9];
    const float* pb  = (const float*)d_in[10];
    float* out = (float*)d_out;

    char* ws = (char*)d_ws;
    unsigned short* h_t = (unsigned short*)(ws);
    unsigned short* o_t = h_t;  // alias: h_t dead after qkv GEMM
    char* q_i8 = (char*)(ws + (16ull << 20));
    char* k_i8 = (char*)(ws + (32ull << 20));
    char* v_f8 = (char*)(ws + (48ull << 20));
    unsigned short* wqkb = (unsigned short*)(ws + (64ull << 20));  // [qw;kw] 1024x512
    unsigned short* wvb = (unsigned short*)(ws + (65ull << 20));
    unsigned short* wpb = wvb + 262144;  // pack4-permuted k-cols
    float* stats  = (float*)(ws + (66ull << 20));
    float* rowsum = (float*)(ws + (66ull << 20) + 65536);
    float* biasqk = (float*)(ws + (66ull << 20) + 131072);
    char* p_f8 = (char*)(ws + (67ull << 20));

    const long long sP  = 2097152;   // 4096*512 elements per batch
    const long long sS  = 16777216;  // 4096*4096 bytes per batch (fp8 P)
    const float QS = 16.f;
    const float SC = 0.044194173824159216f / (QS * QS);
    const float LOG2E = 1.4426950408889634f;

    // setup + gn_stats merged
    pre_kernel<<<1153, 256, 0, stream>>>(x, qw, kw, vw, pw, qb, kb, wqkb, wvb, wpb,
                                         biasqk, rowsum, stats);
    gn_apply_kernel<<<dim3(64, 8, 4), 256, 0, stream>>>(x, stats, gnw, gnb, h_t);
    // merged q|k (1024 blocks) + v (512 blocks)
    gemm_qkv<<<1536, 256, 0, stream>>>(h_t, sP, wqkb, wvb, q_i8, k_i8, v_f8, biasqk, vb, QS);
    // P[q][k] = e4m3(0.25*exp(qk*SC)) pack4, shuffle+atomic rowsums
    gemm_i8_exp<<<dim3(32, 32, 4), 256, 0, stream>>>(q_i8, sP, k_i8, sP, p_f8, sS, rowsum,
                                                     4096, 4096, 512, SC * LOG2E);
    // O_t[q][d] = (P . v^T)/rowsum: fp8 MFMA, pack4-permuted bf16 out, XCD-swizzled
    gemm_fp8_o<<<dim3(512, 1, 1), 256, 0, stream>>>(p_f8, sS, v_f8, sP, o_t, sP, rowsum,
                                                    4096, 512, 4096);
    // y = x + wp~ . O_t^T + pb: M=512(o), N=4096(p), K=512(d, permutation cancels)
    gemm_proj<<<dim3(32, 4, 4), 256, 0, stream>>>(wpb, o_t, sP, out, sP, pb, x, sP,
                                                  512, 4096, 512);
}